// Round 1
// baseline (404.197 us; speedup 1.0000x reference)
//
#include <hip/hip_runtime.h>
#include <hip/hip_bf16.h>
#include <math.h>

#define AS1 __attribute__((address_space(1)))
#define AS3 __attribute__((address_space(3)))

typedef __bf16  bf16x8 __attribute__((ext_vector_type(8)));
typedef float   f32x4  __attribute__((ext_vector_type(4)));
typedef __hip_bfloat16 bf16;

__device__ __forceinline__ void gload_lds16(const void* g, void* l) {
  __builtin_amdgcn_global_load_lds((const AS1 void*)g, (AS3 void*)l, 16, 0, 0);
}

// ---------------- weight conversion f32 -> bf16 ----------------
// layout in dst: qkv_w[196608] | proj_w[65536] | mlp_w1[262144] | mlp_w2[262144]
__global__ __launch_bounds__(256) void k_conv_weights(
    const float* __restrict__ qkvw, const float* __restrict__ projw,
    const float* __restrict__ w1, const float* __restrict__ w2,
    bf16* __restrict__ dst)
{
  int i = blockIdx.x * 256 + threadIdx.x;   // grid covers exactly 786432
  float v;
  if (i < 196608)       v = qkvw[i];
  else if (i < 262144)  v = projw[i - 196608];
  else if (i < 524288)  v = w1[i - 262144];
  else                  v = w2[i - 524288];
  dst[i] = __float2bfloat16(v);
}

// ---------------- rel-pos bias table: btab[h][n][m] ----------------
__global__ __launch_bounds__(256) void k_build_btab(
    const float* __restrict__ rel_bias, float* __restrict__ btab)
{
  int i = blockIdx.x * 256 + threadIdx.x;   // 32768
  int h = i >> 12, r = i & 4095, n = r >> 6, m = r & 63;
  int idx = ((n >> 3) - (m >> 3) + 7) * 15 + ((n & 7) - (m & 7) + 7);
  btab[i] = rel_bias[idx * 8 + h];
}

// ---------------- LN1 + roll(-4,-4) + window partition, f32 -> bf16 ----------------
// token t = win*64 + n ; win = b*64 + wi*8 + wj ; n = i*8 + j
// reads x[b][(wi*8+i+4)%64][(wj*8+j+4)%64][:]
__global__ __launch_bounds__(256) void k_ln1_window(
    const float* __restrict__ x, const float* __restrict__ sc,
    const float* __restrict__ bi, bf16* __restrict__ hout)
{
  int t = blockIdx.x * 4 + (threadIdx.x >> 6);
  int lane = threadIdx.x & 63;
  int win = t >> 6, nn = t & 63;
  int b = win >> 6, ww = win & 63;
  int ry = ((ww >> 3) << 3) + (nn >> 3);
  int rx = ((ww & 7) << 3) + (nn & 7);
  int sy = (ry + 4) & 63, sx = (rx + 4) & 63;
  const float* src = x + ((size_t)(((b << 6) + sy) << 6) + sx) * 256;
  f32x4 v = *(const f32x4*)(src + lane * 4);
  float s = v[0] + v[1] + v[2] + v[3];
  #pragma unroll
  for (int o = 1; o < 64; o <<= 1) s += __shfl_xor(s, o);
  float mu = s * (1.0f / 256.0f);
  float d0 = v[0]-mu, d1 = v[1]-mu, d2 = v[2]-mu, d3 = v[3]-mu;
  float q = d0*d0 + d1*d1 + d2*d2 + d3*d3;
  #pragma unroll
  for (int o = 1; o < 64; o <<= 1) q += __shfl_xor(q, o);
  float rstd = rsqrtf(q * (1.0f / 256.0f) + 1e-5f);
  int c = lane * 4;
  union { bf16 h[4]; uint2 u; } pk;
  pk.h[0] = __float2bfloat16(d0 * rstd * sc[c+0] + bi[c+0]);
  pk.h[1] = __float2bfloat16(d1 * rstd * sc[c+1] + bi[c+1]);
  pk.h[2] = __float2bfloat16(d2 * rstd * sc[c+2] + bi[c+2]);
  pk.h[3] = __float2bfloat16(d3 * rstd * sc[c+3] + bi[c+3]);
  *(uint2*)(hout + (size_t)t * 256 + c) = pk.u;
}

// ---------------- LN2 (pixel-major), f32 -> bf16 ----------------
__global__ __launch_bounds__(256) void k_ln2(
    const float* __restrict__ x1, const float* __restrict__ sc,
    const float* __restrict__ bi, bf16* __restrict__ out)
{
  int t = blockIdx.x * 4 + (threadIdx.x >> 6);
  int lane = threadIdx.x & 63;
  const float* src = x1 + (size_t)t * 256;
  f32x4 v = *(const f32x4*)(src + lane * 4);
  float s = v[0] + v[1] + v[2] + v[3];
  #pragma unroll
  for (int o = 1; o < 64; o <<= 1) s += __shfl_xor(s, o);
  float mu = s * (1.0f / 256.0f);
  float d0 = v[0]-mu, d1 = v[1]-mu, d2 = v[2]-mu, d3 = v[3]-mu;
  float q = d0*d0 + d1*d1 + d2*d2 + d3*d3;
  #pragma unroll
  for (int o = 1; o < 64; o <<= 1) q += __shfl_xor(q, o);
  float rstd = rsqrtf(q * (1.0f / 256.0f) + 1e-5f);
  int c = lane * 4;
  union { bf16 h[4]; uint2 u; } pk;
  pk.h[0] = __float2bfloat16(d0 * rstd * sc[c+0] + bi[c+0]);
  pk.h[1] = __float2bfloat16(d1 * rstd * sc[c+1] + bi[c+1]);
  pk.h[2] = __float2bfloat16(d2 * rstd * sc[c+2] + bi[c+2]);
  pk.h[3] = __float2bfloat16(d3 * rstd * sc[c+3] + bi[c+3]);
  *(uint2*)(out + (size_t)t * 256 + c) = pk.u;
}

// ---------------- generic GEMM: C[M,N] = A[M,K] @ Bw[N,K]^T + bias ----------------
// EPI 0: store bf16
// EPI 1: GELU(exact) -> bf16
// EPI 2: proj: remap token->pixel (inverse window + roll +4), += resid(x), f32 out
// EPI 3: mlp2: Cf[addr] += val (residual already in Cf), f32 out
#define BM 128
#define BN 128
#define BKK 64

template<int EPI>
__global__ __launch_bounds__(256) void k_gemm_bt(
    const bf16* __restrict__ A, const bf16* __restrict__ Bw,
    const float* __restrict__ bias,
    float* __restrict__ Cf, bf16* __restrict__ Cb,
    const float* __restrict__ resid,
    int M, int N, int K)
{
  __shared__ __align__(16) char lds[BM*BKK*2 + BN*BKK*2];  // 16KB + 16KB
  char* ldsA = lds;
  char* ldsB = lds + BM*BKK*2;

  const int tid = threadIdx.x;
  const int wid = tid >> 6;
  const int lane = tid & 63;
  const int l15 = lane & 15, lh = lane >> 4;
  const int rowBase = blockIdx.y * BM;
  const int colBase = blockIdx.x * BN;
  const int wr = (wid >> 1) * 64;
  const int wc = (wid & 1) * 64;

  f32x4 acc[4][4];
  #pragma unroll
  for (int i = 0; i < 4; ++i)
    #pragma unroll
    for (int j = 0; j < 4; ++j) acc[i][j] = (f32x4){0.f,0.f,0.f,0.f};

  for (int k0 = 0; k0 < K; k0 += BKK) {
    // stage A,B tiles (128x64 bf16 each) via global_load_lds, source pre-swizzled
    #pragma unroll
    for (int i = 0; i < 4; ++i) {
      int chunk = i * 4 + wid;                     // 0..15, 1KB per wave-issue
      int off = (chunk * 64 + lane) * 16;          // byte offset in 16KB tile
      int r = off >> 7;                            // tile row (128B/row)
      int cb = off & 127;
      int csw = cb ^ ((r & 7) << 4);               // inverse-swizzled source col
      const char* gA = (const char*)(A + (size_t)(rowBase + r) * K + k0) + csw;
      gload_lds16(gA, ldsA + chunk * 1024);
      const char* gB = (const char*)(Bw + (size_t)(colBase + r) * K + k0) + csw;
      gload_lds16(gB, ldsB + chunk * 1024);
    }
    __syncthreads();
    #pragma unroll
    for (int kk = 0; kk < BKK / 32; ++kk) {
      bf16x8 af[4], bfr[4];
      int kb = kk * 64 + lh * 16;
      #pragma unroll
      for (int m = 0; m < 4; ++m) {
        int rA = wr + m * 16 + l15;
        af[m] = *(const bf16x8*)(ldsA + rA * 128 + (kb ^ ((rA & 7) << 4)));
        int rB = wc + m * 16 + l15;
        bfr[m] = *(const bf16x8*)(ldsB + rB * 128 + (kb ^ ((rB & 7) << 4)));
      }
      #pragma unroll
      for (int m = 0; m < 4; ++m)
        #pragma unroll
        for (int n = 0; n < 4; ++n)
          acc[m][n] = __builtin_amdgcn_mfma_f32_16x16x32_bf16(af[m], bfr[n], acc[m][n], 0, 0, 0);
    }
    __syncthreads();
  }

  // epilogue
  #pragma unroll
  for (int m = 0; m < 4; ++m) {
    #pragma unroll
    for (int n = 0; n < 4; ++n) {
      #pragma unroll
      for (int j = 0; j < 4; ++j) {
        int row = rowBase + wr + m * 16 + lh * 4 + j;
        int col = colBase + wc + n * 16 + l15;
        float v = acc[m][n][j] + bias[col];
        if (EPI == 0) {
          Cb[(size_t)row * N + col] = __float2bfloat16(v);
        } else if (EPI == 1) {
          float g = 0.5f * v * (1.0f + erff(v * 0.70710678118654752f));
          Cb[(size_t)row * N + col] = __float2bfloat16(g);
        } else if (EPI == 2) {
          int win = row >> 6, nn = row & 63;
          int b = win >> 6, ww = win & 63;
          int ry = ((ww >> 3) << 3) + (nn >> 3);
          int rx = ((ww & 7) << 3) + (nn & 7);
          int fy = (ry + 4) & 63, fx = (rx + 4) & 63;
          size_t addr = ((size_t)(((b << 6) + fy) << 6) + fx) * 256 + col;
          Cf[addr] = v + resid[addr];
        } else {
          size_t addr = (size_t)row * N + col;
          Cf[addr] = Cf[addr] + v;
        }
      }
    }
  }
}

// ---------------- attention: 1 wave per (window, head) ----------------
// qkv: [65536][768] bf16 (q|k|v each 256 = h*32+d); out: [65536][256] bf16
__global__ __launch_bounds__(256) void k_attn(
    const bf16* __restrict__ qkv, const float* __restrict__ btab,
    bf16* __restrict__ outp)
{
  __shared__ __align__(16) char smem[71680];
  float* sb = (float*)smem;                        // 64*64 f32 bias for this head
  const int tid = threadIdx.x, wid = tid >> 6, lane = tid & 63;
  const int l15 = lane & 15, lh = lane >> 4;
  const int h = blockIdx.x >> 8;
  const int win = ((blockIdx.x & 255) << 2) + wid;
  const int tb = win << 6;
  char* plw = smem + 16384 + wid * 9216;           // P: 64 rows x 144B (72 bf16)
  char* vtw = smem + 16384 + 36864 + wid * 4608;   // Vt: 32 rows x 144B

  for (int i = tid; i < 4096; i += 256) sb[i] = btab[(h << 12) + i];
  __syncthreads();

  // S = q @ k^T  (M=64 queries, N=64 keys, K=32)
  bf16x8 qf[4], kf[4];
  #pragma unroll
  for (int m = 0; m < 4; ++m) {
    size_t base = (size_t)(tb + m * 16 + l15) * 768 + h * 32 + lh * 8;
    qf[m] = *(const bf16x8*)(qkv + base);
    kf[m] = *(const bf16x8*)(qkv + base + 256);
  }
  f32x4 s[4][4];
  #pragma unroll
  for (int i = 0; i < 4; ++i)
    #pragma unroll
    for (int j = 0; j < 4; ++j) {
      s[i][j] = (f32x4){0.f,0.f,0.f,0.f};
      s[i][j] = __builtin_amdgcn_mfma_f32_16x16x32_bf16(qf[i], kf[j], s[i][j], 0, 0, 0);
    }

  // stage V transposed: vt[d][m]
  #pragma unroll
  for (int it = 0; it < 32; ++it) {
    int idx = it * 64 + lane;
    int m = idx >> 5, d = idx & 31;
    bf16 vv = qkv[(size_t)(tb + m) * 768 + 512 + h * 32 + d];
    *(bf16*)(vtw + d * 144 + m * 2) = vv;
  }

  // softmax (f32, in registers) + write P (bf16, unnormalized) to LDS
  int ww = win & 63, wi = ww >> 3, wj = ww & 7;
  int labm[4];
  #pragma unroll
  for (int jf = 0; jf < 4; ++jf) {
    int m = jf * 16 + l15;
    int yy = wi * 8 + (m >> 3), xx = wj * 8 + (m & 7);
    labm[jf] = (yy < 56 ? 0 : (yy < 60 ? 1 : 2)) * 3 + (xx < 56 ? 0 : (xx < 60 ? 1 : 2));
  }
  float rsum[4][4];
  const float scale = 0.17677669529663687f;  // 1/sqrt(32)
  #pragma unroll
  for (int i = 0; i < 4; ++i) {
    #pragma unroll
    for (int j = 0; j < 4; ++j) {
      int n = i * 16 + lh * 4 + j;
      int yy = wi * 8 + (n >> 3), xx = wj * 8 + (n & 7);
      int labn = (yy < 56 ? 0 : (yy < 60 ? 1 : 2)) * 3 + (xx < 56 ? 0 : (xx < 60 ? 1 : 2));
      float vals[4]; float mx = -1e30f;
      #pragma unroll
      for (int jf = 0; jf < 4; ++jf) {
        int m = jf * 16 + l15;
        float v = s[i][jf][j] * scale + sb[(n << 6) + m];
        if (labn != labm[jf]) v -= 100.0f;
        vals[jf] = v; mx = fmaxf(mx, v);
      }
      #pragma unroll
      for (int o = 1; o < 16; o <<= 1) mx = fmaxf(mx, __shfl_xor(mx, o));
      float sum = 0.0f;
      #pragma unroll
      for (int jf = 0; jf < 4; ++jf) {
        float e = __expf(vals[jf] - mx);
        sum += e;
        *(bf16*)(plw + n * 144 + (jf * 16 + l15) * 2) = __float2bfloat16(e);
      }
      #pragma unroll
      for (int o = 1; o < 16; o <<= 1) sum += __shfl_xor(sum, o);
      rsum[i][j] = sum;
    }
  }
  __syncthreads();

  // O = P @ V  (M=64, N=32, K=64)
  f32x4 o[4][2];
  #pragma unroll
  for (int i = 0; i < 4; ++i) { o[i][0] = (f32x4){0.f,0.f,0.f,0.f}; o[i][1] = (f32x4){0.f,0.f,0.f,0.f}; }
  #pragma unroll
  for (int kk = 0; kk < 2; ++kk) {
    bf16x8 pf[4], vf[2];
    #pragma unroll
    for (int i = 0; i < 4; ++i)
      pf[i] = *(const bf16x8*)(plw + (i * 16 + l15) * 144 + kk * 64 + lh * 16);
    #pragma unroll
    for (int df = 0; df < 2; ++df)
      vf[df] = *(const bf16x8*)(vtw + (df * 16 + l15) * 144 + kk * 64 + lh * 16);
    #pragma unroll
    for (int i = 0; i < 4; ++i)
      #pragma unroll
      for (int df = 0; df < 2; ++df)
        o[i][df] = __builtin_amdgcn_mfma_f32_16x16x32_bf16(pf[i], vf[df], o[i][df], 0, 0, 0);
  }
  #pragma unroll
  for (int i = 0; i < 4; ++i)
    #pragma unroll
    for (int df = 0; df < 2; ++df)
      #pragma unroll
      for (int j = 0; j < 4; ++j) {
        int n = i * 16 + lh * 4 + j;
        int d = df * 16 + l15;
        float v = o[i][df][j] / rsum[i][j];
        outp[(size_t)(tb + n) * 256 + h * 32 + d] = __float2bfloat16(v);
      }
}

// ---------------- launch ----------------
extern "C" void kernel_launch(void* const* d_in, const int* in_sizes, int n_in,
                              void* d_out, int out_size, void* d_ws, size_t ws_size,
                              hipStream_t stream) {
  (void)in_sizes; (void)n_in; (void)out_size; (void)ws_size;
  const float* x      = (const float*)d_in[0];
  const float* ln1_s  = (const float*)d_in[1];
  const float* ln1_b  = (const float*)d_in[2];
  const float* qkv_w  = (const float*)d_in[3];
  const float* qkv_b  = (const float*)d_in[4];
  const float* proj_w = (const float*)d_in[5];
  const float* proj_b = (const float*)d_in[6];
  const float* rel_b  = (const float*)d_in[7];
  const float* ln2_s  = (const float*)d_in[8];
  const float* ln2_b  = (const float*)d_in[9];
  const float* w1     = (const float*)d_in[10];
  const float* b1     = (const float*)d_in[11];
  const float* w2     = (const float*)d_in[12];
  const float* b2     = (const float*)d_in[13];

  char* ws = (char*)d_ws;
  bf16*  wqkv  = (bf16*)(ws + 0);               // 196608 el
  bf16*  wproj = wqkv + 196608;                 // 65536 el
  bf16*  wm1   = wqkv + 262144;                 // 262144 el
  bf16*  wm2   = wqkv + 524288;                 // 262144 el
  float* btab  = (float*)(ws + 1572864);        // 32768 f32
  bf16*  hbuf  = (bf16*)(ws + 2097152);         // 65536x256
  bf16*  qkvb  = (bf16*)(ws + 35651584);        // 65536x768
  bf16*  attnb = (bf16*)(ws + 136314880);       // 65536x256
  bf16*  ln2buf = hbuf;                         // reuse (h dead after QKV gemm)
  bf16*  actb  = qkvb;                          // reuse (qkv/attn dead after proj)
  float* x1    = (float*)d_out;                 // residual lives in d_out

  k_conv_weights<<<3072, 256, 0, stream>>>(qkv_w, proj_w, w1, w2, wqkv);
  k_build_btab<<<128, 256, 0, stream>>>(rel_b, btab);
  k_ln1_window<<<16384, 256, 0, stream>>>(x, ln1_s, ln1_b, hbuf);
  k_gemm_bt<0><<<dim3(6, 512), 256, 0, stream>>>(hbuf, wqkv, qkv_b, nullptr, qkvb, nullptr, 65536, 768, 256);
  k_attn<<<2048, 256, 0, stream>>>(qkvb, btab, attnb);
  k_gemm_bt<2><<<dim3(2, 512), 256, 0, stream>>>(attnb, wproj, proj_b, x1, nullptr, x, 65536, 256, 256);
  k_ln2<<<16384, 256, 0, stream>>>(x1, ln2_s, ln2_b, ln2buf);
  k_gemm_bt<1><<<dim3(8, 512), 256, 0, stream>>>(ln2buf, wm1, b1, nullptr, actb, nullptr, 65536, 1024, 256);
  k_gemm_bt<3><<<dim3(2, 512), 256, 0, stream>>>(actb, wm2, b2, x1, nullptr, nullptr, 65536, 256, 1024);
}

// Round 2
// 364.688 us; speedup vs baseline: 1.1083x; 1.1083x over previous
//
#include <hip/hip_runtime.h>
#include <hip/hip_bf16.h>
#include <math.h>

#define AS1 __attribute__((address_space(1)))
#define AS3 __attribute__((address_space(3)))

typedef __bf16  bf16x8 __attribute__((ext_vector_type(8)));
typedef float   f32x4  __attribute__((ext_vector_type(4)));
typedef __hip_bfloat16 bf16;

__device__ __forceinline__ void gload_lds16(const void* g, void* l) {
  __builtin_amdgcn_global_load_lds((const AS1 void*)g, (AS3 void*)l, 16, 0, 0);
}

// ---------------- weight conversion f32 -> bf16 ----------------
// layout in dst: qkv_w[196608] | proj_w[65536] | mlp_w1[262144] | mlp_w2[262144]
__global__ __launch_bounds__(256) void k_conv_weights(
    const float* __restrict__ qkvw, const float* __restrict__ projw,
    const float* __restrict__ w1, const float* __restrict__ w2,
    bf16* __restrict__ dst)
{
  int i = blockIdx.x * 256 + threadIdx.x;   // grid covers exactly 786432
  float v;
  if (i < 196608)       v = qkvw[i];
  else if (i < 262144)  v = projw[i - 196608];
  else if (i < 524288)  v = w1[i - 262144];
  else                  v = w2[i - 524288];
  dst[i] = __float2bfloat16(v);
}

// ---------------- rel-pos bias table: btab[h][n][m] ----------------
__global__ __launch_bounds__(256) void k_build_btab(
    const float* __restrict__ rel_bias, float* __restrict__ btab)
{
  int i = blockIdx.x * 256 + threadIdx.x;   // 32768
  int h = i >> 12, r = i & 4095, n = r >> 6, m = r & 63;
  int idx = ((n >> 3) - (m >> 3) + 7) * 15 + ((n & 7) - (m & 7) + 7);
  btab[i] = rel_bias[idx * 8 + h];
}

// ---------------- LN1 + roll(-4,-4) + window partition, f32 -> bf16 ----------------
__global__ __launch_bounds__(256) void k_ln1_window(
    const float* __restrict__ x, const float* __restrict__ sc,
    const float* __restrict__ bi, bf16* __restrict__ hout)
{
  int t = blockIdx.x * 4 + (threadIdx.x >> 6);
  int lane = threadIdx.x & 63;
  int win = t >> 6, nn = t & 63;
  int b = win >> 6, ww = win & 63;
  int ry = ((ww >> 3) << 3) + (nn >> 3);
  int rx = ((ww & 7) << 3) + (nn & 7);
  int sy = (ry + 4) & 63, sx = (rx + 4) & 63;
  const float* src = x + ((size_t)(((b << 6) + sy) << 6) + sx) * 256;
  f32x4 v = *(const f32x4*)(src + lane * 4);
  float s = v[0] + v[1] + v[2] + v[3];
  #pragma unroll
  for (int o = 1; o < 64; o <<= 1) s += __shfl_xor(s, o);
  float mu = s * (1.0f / 256.0f);
  float d0 = v[0]-mu, d1 = v[1]-mu, d2 = v[2]-mu, d3 = v[3]-mu;
  float q = d0*d0 + d1*d1 + d2*d2 + d3*d3;
  #pragma unroll
  for (int o = 1; o < 64; o <<= 1) q += __shfl_xor(q, o);
  float rstd = rsqrtf(q * (1.0f / 256.0f) + 1e-5f);
  int c = lane * 4;
  union { bf16 h[4]; uint2 u; } pk;
  pk.h[0] = __float2bfloat16(d0 * rstd * sc[c+0] + bi[c+0]);
  pk.h[1] = __float2bfloat16(d1 * rstd * sc[c+1] + bi[c+1]);
  pk.h[2] = __float2bfloat16(d2 * rstd * sc[c+2] + bi[c+2]);
  pk.h[3] = __float2bfloat16(d3 * rstd * sc[c+3] + bi[c+3]);
  *(uint2*)(hout + (size_t)t * 256 + c) = pk.u;
}

// ---------------- LN2 (pixel-major), f32 -> bf16 ----------------
__global__ __launch_bounds__(256) void k_ln2(
    const float* __restrict__ x1, const float* __restrict__ sc,
    const float* __restrict__ bi, bf16* __restrict__ out)
{
  int t = blockIdx.x * 4 + (threadIdx.x >> 6);
  int lane = threadIdx.x & 63;
  const float* src = x1 + (size_t)t * 256;
  f32x4 v = *(const f32x4*)(src + lane * 4);
  float s = v[0] + v[1] + v[2] + v[3];
  #pragma unroll
  for (int o = 1; o < 64; o <<= 1) s += __shfl_xor(s, o);
  float mu = s * (1.0f / 256.0f);
  float d0 = v[0]-mu, d1 = v[1]-mu, d2 = v[2]-mu, d3 = v[3]-mu;
  float q = d0*d0 + d1*d1 + d2*d2 + d3*d3;
  #pragma unroll
  for (int o = 1; o < 64; o <<= 1) q += __shfl_xor(q, o);
  float rstd = rsqrtf(q * (1.0f / 256.0f) + 1e-5f);
  int c = lane * 4;
  union { bf16 h[4]; uint2 u; } pk;
  pk.h[0] = __float2bfloat16(d0 * rstd * sc[c+0] + bi[c+0]);
  pk.h[1] = __float2bfloat16(d1 * rstd * sc[c+1] + bi[c+1]);
  pk.h[2] = __float2bfloat16(d2 * rstd * sc[c+2] + bi[c+2]);
  pk.h[3] = __float2bfloat16(d3 * rstd * sc[c+3] + bi[c+3]);
  *(uint2*)(out + (size_t)t * 256 + c) = pk.u;
}

// ---------------- generic GEMM: C[M,N] = A[M,K] @ Bw[N,K]^T + bias ----------------
// Swapped-operand MFMA: acc[m][n] fragment holds, per lane, 4 CONSECUTIVE cols
// of C at row (wr+m*16+l15), cols (wc+n*16+lh*4 .. +3)  -> vector epilogue.
// EPI 0: store bf16
// EPI 1: GELU(tanh-approx) -> bf16
// EPI 2: proj: remap token->pixel (inverse window + roll +4), += resid(x), f32 out
// EPI 3: mlp2: Cf[addr] += val (residual already in Cf), f32 out
#define BM 128
#define BN 128
#define BKK 64

template<int EPI>
__global__ __launch_bounds__(256) void k_gemm_bt(
    const bf16* __restrict__ A, const bf16* __restrict__ Bw,
    const float* __restrict__ bias,
    float* __restrict__ Cf, bf16* __restrict__ Cb,
    const float* __restrict__ resid,
    int M, int N, int K)
{
  __shared__ __align__(16) char lds[BM*BKK*2 + BN*BKK*2];  // 16KB + 16KB
  char* ldsA = lds;
  char* ldsB = lds + BM*BKK*2;

  const int tid = threadIdx.x;
  const int wid = tid >> 6;
  const int lane = tid & 63;
  const int l15 = lane & 15, lh = lane >> 4;
  const int rowBase = blockIdx.y * BM;
  const int colBase = blockIdx.x * BN;
  const int wr = (wid >> 1) * 64;
  const int wc = (wid & 1) * 64;

  f32x4 acc[4][4];
  #pragma unroll
  for (int i = 0; i < 4; ++i)
    #pragma unroll
    for (int j = 0; j < 4; ++j) acc[i][j] = (f32x4){0.f,0.f,0.f,0.f};

  for (int k0 = 0; k0 < K; k0 += BKK) {
    // stage A,B tiles (128x64 bf16 each) via global_load_lds, source pre-swizzled
    #pragma unroll
    for (int i = 0; i < 4; ++i) {
      int chunk = i * 4 + wid;                     // 0..15, 1KB per wave-issue
      int off = (chunk * 64 + lane) * 16;          // byte offset in 16KB tile
      int r = off >> 7;                            // tile row (128B/row)
      int cb = off & 127;
      int csw = cb ^ ((r & 7) << 4);               // inverse-swizzled source col
      const char* gA = (const char*)(A + (size_t)(rowBase + r) * K + k0) + csw;
      gload_lds16(gA, ldsA + chunk * 1024);
      const char* gB = (const char*)(Bw + (size_t)(colBase + r) * K + k0) + csw;
      gload_lds16(gB, ldsB + chunk * 1024);
    }
    __syncthreads();
    #pragma unroll
    for (int kk = 0; kk < BKK / 32; ++kk) {
      bf16x8 af[4], bfr[4];
      int kb = kk * 64 + lh * 16;
      #pragma unroll
      for (int m = 0; m < 4; ++m) {
        int rA = wr + m * 16 + l15;
        af[m] = *(const bf16x8*)(ldsA + rA * 128 + (kb ^ ((rA & 7) << 4)));
        int rB = wc + m * 16 + l15;
        bfr[m] = *(const bf16x8*)(ldsB + rB * 128 + (kb ^ ((rB & 7) << 4)));
      }
      #pragma unroll
      for (int m = 0; m < 4; ++m)
        #pragma unroll
        for (int n = 0; n < 4; ++n)
          acc[m][n] = __builtin_amdgcn_mfma_f32_16x16x32_bf16(bfr[n], af[m], acc[m][n], 0, 0, 0);
    }
    __syncthreads();
  }

  // epilogue: acc[m][n] -> C[rowBase+wr+m*16+l15][colBase+wc+n*16+lh*4 + (0..3)]
  #pragma unroll
  for (int m = 0; m < 4; ++m) {
    const int row = rowBase + wr + m * 16 + l15;
    size_t rowAddr;
    if (EPI == 2) {
      int win = row >> 6, nn = row & 63;
      int b = win >> 6, ww = win & 63;
      int ry = ((ww >> 3) << 3) + (nn >> 3);
      int rx = ((ww & 7) << 3) + (nn & 7);
      int fy = (ry + 4) & 63, fx = (rx + 4) & 63;
      rowAddr = ((size_t)(((b << 6) + fy) << 6) + fx) * 256;
    } else {
      rowAddr = (size_t)row * N;
    }
    #pragma unroll
    for (int n = 0; n < 4; ++n) {
      const int colb = colBase + wc + n * 16 + lh * 4;
      const f32x4 b4 = *(const f32x4*)(bias + colb);
      f32x4 v4;
      #pragma unroll
      for (int j = 0; j < 4; ++j) v4[j] = acc[m][n][j] + b4[j];
      if (EPI == 0) {
        union { bf16 h[4]; uint2 u; } pk;
        #pragma unroll
        for (int j = 0; j < 4; ++j) pk.h[j] = __float2bfloat16(v4[j]);
        *(uint2*)(Cb + rowAddr + colb) = pk.u;
      } else if (EPI == 1) {
        union { bf16 h[4]; uint2 u; } pk;
        #pragma unroll
        for (int j = 0; j < 4; ++j) {
          float v = v4[j];
          // gelu(v) ~= v * sigmoid(1.59577*v + 0.0713548*v^3)
          float u2 = v * (1.5957691216057308f + 0.07135481627f * v * v);
          float g = v / (1.0f + __expf(-u2));
          pk.h[j] = __float2bfloat16(g);
        }
        *(uint2*)(Cb + rowAddr + colb) = pk.u;
      } else if (EPI == 2) {
        const f32x4 r4 = *(const f32x4*)(resid + rowAddr + colb);
        f32x4 o4;
        #pragma unroll
        for (int j = 0; j < 4; ++j) o4[j] = v4[j] + r4[j];
        *(f32x4*)(Cf + rowAddr + colb) = o4;
      } else {
        f32x4* p = (f32x4*)(Cf + rowAddr + colb);
        f32x4 c = *p;
        #pragma unroll
        for (int j = 0; j < 4; ++j) c[j] += v4[j];
        *p = c;
      }
    }
  }
}

// ---------------- attention: 1 wave per (window, head) ----------------
// qkv: [65536][768] bf16 (q|k|v each 256 = h*32+d); out: [65536][256] bf16
__global__ __launch_bounds__(256) void k_attn(
    const bf16* __restrict__ qkv, const float* __restrict__ btab,
    bf16* __restrict__ outp)
{
  __shared__ __align__(16) char smem[71680];
  float* sb = (float*)smem;                        // 64*64 f32 bias for this head
  const int tid = threadIdx.x, wid = tid >> 6, lane = tid & 63;
  const int l15 = lane & 15, lh = lane >> 4;
  const int h = blockIdx.x >> 8;
  const int win = ((blockIdx.x & 255) << 2) + wid;
  const int tb = win << 6;
  char* plw = smem + 16384 + wid * 9216;           // P: 64 rows x 144B (72 bf16)
  char* vtw = smem + 16384 + 36864 + wid * 4608;   // Vt: 32 rows x 144B

  for (int i = tid; i < 4096; i += 256) sb[i] = btab[(h << 12) + i];
  __syncthreads();

  // S = q @ k^T  (M=64 queries, N=64 keys, K=32)
  bf16x8 qf[4], kf[4];
  #pragma unroll
  for (int m = 0; m < 4; ++m) {
    size_t base = (size_t)(tb + m * 16 + l15) * 768 + h * 32 + lh * 8;
    qf[m] = *(const bf16x8*)(qkv + base);
    kf[m] = *(const bf16x8*)(qkv + base + 256);
  }
  f32x4 s[4][4];
  #pragma unroll
  for (int i = 0; i < 4; ++i)
    #pragma unroll
    for (int j = 0; j < 4; ++j) {
      s[i][j] = (f32x4){0.f,0.f,0.f,0.f};
      s[i][j] = __builtin_amdgcn_mfma_f32_16x16x32_bf16(qf[i], kf[j], s[i][j], 0, 0, 0);
    }

  // stage V transposed: vt[d][m]
  #pragma unroll
  for (int it = 0; it < 32; ++it) {
    int idx = it * 64 + lane;
    int m = idx >> 5, d = idx & 31;
    bf16 vv = qkv[(size_t)(tb + m) * 768 + 512 + h * 32 + d];
    *(bf16*)(vtw + d * 144 + m * 2) = vv;
  }

  // softmax (f32, in registers) + write P (bf16, unnormalized) to LDS
  int ww = win & 63, wi = ww >> 3, wj = ww & 7;
  int labm[4];
  #pragma unroll
  for (int jf = 0; jf < 4; ++jf) {
    int m = jf * 16 + l15;
    int yy = wi * 8 + (m >> 3), xx = wj * 8 + (m & 7);
    labm[jf] = (yy < 56 ? 0 : (yy < 60 ? 1 : 2)) * 3 + (xx < 56 ? 0 : (xx < 60 ? 1 : 2));
  }
  float rsum[4][4];
  const float scale = 0.17677669529663687f;  // 1/sqrt(32)
  #pragma unroll
  for (int i = 0; i < 4; ++i) {
    #pragma unroll
    for (int j = 0; j < 4; ++j) {
      int n = i * 16 + lh * 4 + j;
      int yy = wi * 8 + (n >> 3), xx = wj * 8 + (n & 7);
      int labn = (yy < 56 ? 0 : (yy < 60 ? 1 : 2)) * 3 + (xx < 56 ? 0 : (xx < 60 ? 1 : 2));
      float vals[4]; float mx = -1e30f;
      #pragma unroll
      for (int jf = 0; jf < 4; ++jf) {
        int m = jf * 16 + l15;
        float v = s[i][jf][j] * scale + sb[(n << 6) + m];
        if (labn != labm[jf]) v -= 100.0f;
        vals[jf] = v; mx = fmaxf(mx, v);
      }
      #pragma unroll
      for (int o = 1; o < 16; o <<= 1) mx = fmaxf(mx, __shfl_xor(mx, o));
      float sum = 0.0f;
      #pragma unroll
      for (int jf = 0; jf < 4; ++jf) {
        float e = __expf(vals[jf] - mx);
        sum += e;
        *(bf16*)(plw + n * 144 + (jf * 16 + l15) * 2) = __float2bfloat16(e);
      }
      #pragma unroll
      for (int o = 1; o < 16; o <<= 1) sum += __shfl_xor(sum, o);
      rsum[i][j] = sum;
    }
  }
  __syncthreads();

  // O = P @ V  (M=64, N=32, K=64)
  f32x4 o[4][2];
  #pragma unroll
  for (int i = 0; i < 4; ++i) { o[i][0] = (f32x4){0.f,0.f,0.f,0.f}; o[i][1] = (f32x4){0.f,0.f,0.f,0.f}; }
  #pragma unroll
  for (int kk = 0; kk < 2; ++kk) {
    bf16x8 pf[4], vf[2];
    #pragma unroll
    for (int i = 0; i < 4; ++i)
      pf[i] = *(const bf16x8*)(plw + (i * 16 + l15) * 144 + kk * 64 + lh * 16);
    #pragma unroll
    for (int df = 0; df < 2; ++df)
      vf[df] = *(const bf16x8*)(vtw + (df * 16 + l15) * 144 + kk * 64 + lh * 16);
    #pragma unroll
    for (int i = 0; i < 4; ++i)
      #pragma unroll
      for (int df = 0; df < 2; ++df)
        o[i][df] = __builtin_amdgcn_mfma_f32_16x16x32_bf16(pf[i], vf[df], o[i][df], 0, 0, 0);
  }
  #pragma unroll
  for (int i = 0; i < 4; ++i)
    #pragma unroll
    for (int df = 0; df < 2; ++df)
      #pragma unroll
      for (int j = 0; j < 4; ++j) {
        int n = i * 16 + lh * 4 + j;
        int d = df * 16 + l15;
        float v = o[i][df][j] / rsum[i][j];
        outp[(size_t)(tb + n) * 256 + h * 32 + d] = __float2bfloat16(v);
      }
}

// ---------------- launch ----------------
extern "C" void kernel_launch(void* const* d_in, const int* in_sizes, int n_in,
                              void* d_out, int out_size, void* d_ws, size_t ws_size,
                              hipStream_t stream) {
  (void)in_sizes; (void)n_in; (void)out_size; (void)ws_size;
  const float* x      = (const float*)d_in[0];
  const float* ln1_s  = (const float*)d_in[1];
  const float* ln1_b  = (const float*)d_in[2];
  const float* qkv_w  = (const float*)d_in[3];
  const float* qkv_b  = (const float*)d_in[4];
  const float* proj_w = (const float*)d_in[5];
  const float* proj_b = (const float*)d_in[6];
  const float* rel_b  = (const float*)d_in[7];
  const float* ln2_s  = (const float*)d_in[8];
  const float* ln2_b  = (const float*)d_in[9];
  const float* w1     = (const float*)d_in[10];
  const float* b1     = (const float*)d_in[11];
  const float* w2     = (const float*)d_in[12];
  const float* b2     = (const float*)d_in[13];

  char* ws = (char*)d_ws;
  bf16*  wqkv  = (bf16*)(ws + 0);               // 196608 el
  bf16*  wproj = wqkv + 196608;                 // 65536 el
  bf16*  wm1   = wqkv + 262144;                 // 262144 el
  bf16*  wm2   = wqkv + 524288;                 // 262144 el
  float* btab  = (float*)(ws + 1572864);        // 32768 f32
  bf16*  hbuf  = (bf16*)(ws + 2097152);         // 65536x256
  bf16*  qkvb  = (bf16*)(ws + 35651584);        // 65536x768
  bf16*  attnb = (bf16*)(ws + 136314880);       // 65536x256
  bf16*  ln2buf = hbuf;                         // reuse (h dead after QKV gemm)
  bf16*  actb  = qkvb;                          // reuse (qkv/attn dead after proj)
  float* x1    = (float*)d_out;                 // residual lives in d_out

  k_conv_weights<<<3072, 256, 0, stream>>>(qkv_w, proj_w, w1, w2, wqkv);
  k_build_btab<<<128, 256, 0, stream>>>(rel_b, btab);
  k_ln1_window<<<16384, 256, 0, stream>>>(x, ln1_s, ln1_b, hbuf);
  k_gemm_bt<0><<<dim3(6, 512), 256, 0, stream>>>(hbuf, wqkv, qkv_b, nullptr, qkvb, nullptr, 65536, 768, 256);
  k_attn<<<2048, 256, 0, stream>>>(qkvb, btab, attnb);
  k_gemm_bt<2><<<dim3(2, 512), 256, 0, stream>>>(attnb, wproj, proj_b, x1, nullptr, x, 65536, 256, 256);
  k_ln2<<<16384, 256, 0, stream>>>(x1, ln2_s, ln2_b, ln2buf);
  k_gemm_bt<1><<<dim3(8, 512), 256, 0, stream>>>(ln2buf, wm1, b1, nullptr, actb, nullptr, 65536, 1024, 256);
  k_gemm_bt<3><<<dim3(2, 512), 256, 0, stream>>>(actb, wm2, b2, x1, nullptr, nullptr, 65536, 256, 1024);
}